// Round 11
// baseline (631.219 us; speedup 1.0000x reference)
//
#include <hip/hip_runtime.h>

#define N_VOX 50000
#define BATCH 2
#define DD 8
#define HH 160
#define WW 160
#define PD 10
#define PH 162
#define PW 162
#define KK 27
#define NCELL (BATCH*DD*HH*WW)         // 409600 = 400*1024
#define GRID_ELEMS (BATCH*PD*PH*PW)    // 524880
#define OUT_ELEMS (BATCH*128*DD*HH*WW) // 52,428,800

typedef __attribute__((ext_vector_type(8))) short short8v;
typedef __attribute__((ext_vector_type(4))) float float4v;

__device__ inline unsigned short f2bf(float f) {
    unsigned u = __float_as_uint(f);
    u += 0x7FFFu + ((u >> 16) & 1u);
    return (unsigned short)(u >> 16);
}
__device__ inline float bf2f(unsigned short b) {
    return __uint_as_float((unsigned)b << 16);
}

__device__ inline void gload_lds16(const void* g, void* l) {
    __builtin_amdgcn_global_load_lds(
        (const __attribute__((address_space(1))) void*)g,
        (__attribute__((address_space(3))) void*)l, 16, 0, 0);
}

// ============ spatial sort: occupancy flags -> prefix sum -> permutation ====
__global__ void k_flags(const int* __restrict__ coors, int* __restrict__ flags) {
    int n = blockIdx.x * 256 + threadIdx.x;
    if (n >= N_VOX) return;
    int b = coors[n*4+0], z = coors[n*4+1], y = coors[n*4+2], x = coors[n*4+3];
    flags[((b*DD + z)*HH + y)*WW + x] = 1;
}

__global__ void k_scan1(const int* __restrict__ flags, int* __restrict__ scanout,
                        int* __restrict__ bsums) {
    __shared__ int s[256];
    int t = threadIdx.x, blk = blockIdx.x;
    int4 v = ((const int4*)(flags + blk*1024))[t];
    int tsum = v.x + v.y + v.z + v.w;
    s[t] = tsum; __syncthreads();
    for (int off = 1; off < 256; off <<= 1) {
        int x = (t >= off) ? s[t-off] : 0;
        __syncthreads(); s[t] += x; __syncthreads();
    }
    int excl = s[t] - tsum;
    int4 o; o.x = excl; o.y = excl + v.x; o.z = o.y + v.y; o.w = o.z + v.z;
    ((int4*)(scanout + blk*1024))[t] = o;
    if (t == 255) bsums[blk] = s[255];
}

__global__ void k_scan2(int* __restrict__ bsums) {
    __shared__ int s[512];
    int t = threadIdx.x;
    int orig = (t < 400) ? bsums[t] : 0;
    s[t] = orig; __syncthreads();
    for (int off = 1; off < 512; off <<= 1) {
        int x = (t >= off) ? s[t-off] : 0;
        __syncthreads(); s[t] += x; __syncthreads();
    }
    if (t < 400) bsums[t] = s[t] - orig;
}

// ============ k_pos: permutation + gridP + phi in ONE pass ==================
__global__ void k_pos(const float* __restrict__ vf, const int* __restrict__ coors,
                      const int* __restrict__ scanout, const int* __restrict__ bsums,
                      int* __restrict__ vox_at, int* __restrict__ gridP,
                      unsigned short* __restrict__ phi) {
    int n = blockIdx.x * 256 + threadIdx.x;
    if (n > N_VOX) return;
    if (n == N_VOX) {                      // pad row = phi(0)
        ushort4 p;
        p.x = f2bf(0.f);
        p.y = f2bf(__expf(-1.f));
        p.z = f2bf(1.f);
        p.w = f2bf(__expf(-1.f));
        #pragma unroll
        for (int c = 0; c < 16; ++c)
            *(ushort4*)&phi[((size_t)N_VOX * 16 + c) * 4] = p;
        return;
    }
    int b = coors[n*4+0], z = coors[n*4+1], y = coors[n*4+2], x = coors[n*4+3];
    int lin = ((b*DD + z)*HH + y)*WW + x;
    int pos = scanout[lin] + bsums[lin >> 10];
    vox_at[pos] = n;
    gridP[((b*PD + z+1)*PH + (y+1))*PW + (x+1)] = pos;
    #pragma unroll
    for (int c = 0; c < 16; ++c) {
        float xv = vf[(size_t)n * 16 + c];
        float sig = 1.f / (1.f + __expf(-xv));
        ushort4 p;
        p.x = f2bf(xv * sig);
        p.y = f2bf(__expf(-(xv + 1.f) * (xv + 1.f)));
        p.z = f2bf(__expf(-xv * xv));
        p.w = f2bf(__expf(-(xv - 1.f) * (xv - 1.f)));
        *(ushort4*)&phi[((size_t)pos * 16 + c) * 4] = p;
    }
}

// iterate permuted index -> coalesced nbrP writes
__global__ void k_nbrP(const int* __restrict__ coors, const int* __restrict__ vox_at,
                       const int* __restrict__ gridP, int* __restrict__ nbrP) {
    int i = blockIdx.x * 256 + threadIdx.x;
    if (i >= N_VOX) return;
    int n = vox_at[i];
    int b = coors[n*4+0], z = coors[n*4+1]+1, y = coors[n*4+2]+1, x = coors[n*4+3]+1;
    int k = 0;
    for (int dz = -1; dz <= 1; ++dz)
        for (int dy = -1; dy <= 1; ++dy)
            for (int dx = -1; dx <= 1; ++dx) {
                int g = gridP[((b*PD + z+dz)*PH + (y+dy))*PW + (x+dx)];
                nbrP[k*N_VOX + i] = (g >= 0) ? g : N_VOX;
                ++k;
            }
}

// ============ all 5 layers' weight swizzle in ONE dispatch ============
struct WswzArgs {
    const float* wb[5];
    const float* ws[5];
    unsigned short* dst[5];
};
__global__ void k_wswz_all(WswzArgs a) {
    constexpr int off[6]   = {0, 27648, 82944, 304128, 746496, 1631232};
    constexpr int lgCI4[5] = {6, 6, 7, 8, 8};
    constexpr int lgCO[5]  = {4, 5, 6, 6, 7};
    int e = blockIdx.x * 256 + threadIdx.x;
    if (e >= off[5]) return;
    int L = 0;
    #pragma unroll
    for (int i = 1; i < 5; ++i) L += (e >= off[i]);
    int el = e - off[L];
    int CIN4 = 1 << lgCI4[L], COUT = 1 << lgCO[L], CIN = CIN4 >> 2;
    int j8   = el & 7;
    int rest = el >> 3;
    int o    = rest & (COUT - 1);
    int kb   = rest >> lgCO[L];
    int kabs = kb * 8 + j8;
    int k  = kabs >> lgCI4[L];
    int c4 = kabs & (CIN4 - 1);
    int c = c4 >> 2, jj = c4 & 3;
    float v = (jj == 0) ? a.wb[L][(k * CIN + c) * COUT + o]
                        : a.ws[L][((k * CIN + c) * 3 + (jj - 1)) * COUT + o];
    a.dst[L][el] = f2bf(v);
}

// ============ 1-wave MFMA conv, M=64 per wave (in/e1; bf16 pre out) =========
template<int CIN, int COUT, int NSPL>
__global__ __launch_bounds__(64, 2) void k_conv_mfma(
    const unsigned short* __restrict__ phi,
    const int*            __restrict__ nbrP,
    const unsigned short* __restrict__ Wsw,
    unsigned short*       __restrict__ preB,   // bf16 pre (non-last layers)
    float*                __restrict__ sums)
{
    constexpr int CIN4   = CIN * 4;
    constexpr int BK     = 64;
    constexpr int SPK    = CIN4 / BK;
    constexpr int NSTAGE = KK * SPK;
    constexpr int COUTH  = COUT / NSPL;
    constexpr int NFW    = COUTH / 16;
    constexpr int WR     = 4;
    constexpr int NMB    = (N_VOX + 63) / 64;
    constexpr int NBLK   = NMB * NSPL;
    constexpr int PERX   = (NBLK + 7) / 8;

    int lb = blockIdx.x;
    int linear = (lb & 7) * PERX + (lb >> 3);
    if (linear >= NBLK) return;
    const int mb = linear / NSPL, h = linear % NSPL;

    const int lane = threadIdx.x & 63;
    const int l15 = lane & 15, q = lane >> 4;
    const int base = mb * 64;
    int vg[WR];
    #pragma unroll
    for (int rs = 0; rs < WR; ++rs) vg[rs] = base + rs * 16 + l15;
    const int ob = h * COUTH;

    const unsigned short* bp = Wsw + (size_t)(q * COUT + ob + l15) * 8;

    int rows[WR], rowsN[WR];
    short8v A0[2][WR], A1[2][WR];
    short8v B0[2][NFW], B1[2][NFW];

    auto loadB = [&](int sp, short8v (&Bb)[2][NFW]) {
        #pragma unroll
        for (int kk = 0; kk < 2; ++kk)
            #pragma unroll
            for (int nf = 0; nf < NFW; ++nf)
                Bb[kk][nf] = *(const short8v*)(bp +
                    ((size_t)(sp * 8 + kk * 4) * COUT + nf * 16) * 8);
    };
    auto loadA = [&](int sp, short8v (&Ab)[2][WR]) {
        if (sp % SPK == 0) {
            #pragma unroll
            for (int rs = 0; rs < WR; ++rs) rows[rs] = rowsN[rs];
        }
        const int c4s = (sp % SPK) * BK;
        #pragma unroll
        for (int rs = 0; rs < WR; ++rs) {
            const unsigned short* p = phi + (size_t)rows[rs] * CIN4 + c4s + q * 8;
            Ab[0][rs] = *(const short8v*)p;
            Ab[1][rs] = *(const short8v*)(p + 32);
        }
        if (sp % SPK == 0) {
            int k2 = sp / SPK + 1;
            if (k2 < KK) {
                #pragma unroll
                for (int rs = 0; rs < WR; ++rs)
                    rowsN[rs] = (vg[rs] < N_VOX) ? nbrP[k2 * N_VOX + vg[rs]] : N_VOX;
            }
        }
    };

    float4v acc[WR][NFW];
    #pragma unroll
    for (int rs = 0; rs < WR; ++rs)
        #pragma unroll
        for (int nf = 0; nf < NFW; ++nf)
            acc[rs][nf] = (float4v){0.f, 0.f, 0.f, 0.f};

    auto domfma = [&](const short8v (&Ab)[2][WR], const short8v (&Bb)[2][NFW]) {
        #pragma unroll
        for (int kk = 0; kk < 2; ++kk)
            #pragma unroll
            for (int nf = 0; nf < NFW; ++nf)
                #pragma unroll
                for (int rs = 0; rs < WR; ++rs)
                    acc[rs][nf] = __builtin_amdgcn_mfma_f32_16x16x32_bf16(
                        Ab[kk][rs], Bb[kk][nf], acc[rs][nf], 0, 0, 0);
    };

    #pragma unroll
    for (int rs = 0; rs < WR; ++rs) {
        rows[rs]  = (vg[rs] < N_VOX) ? nbrP[vg[rs]] : N_VOX;
        rowsN[rs] = (vg[rs] < N_VOX) ? nbrP[N_VOX + vg[rs]] : N_VOX;
    }
    loadB(0, B0);
    #pragma unroll
    for (int rs = 0; rs < WR; ++rs) {
        const unsigned short* p = phi + (size_t)rows[rs] * CIN4 + q * 8;
        A0[0][rs] = *(const short8v*)p;
        A0[1][rs] = *(const short8v*)(p + 32);
    }

    #define SLOT(T, Ac, Bc, An, Bn)                                   \
        if ((T) + 1 < NSTAGE) { loadB((T) + 1, Bn); loadA((T) + 1, An); } \
        __builtin_amdgcn_sched_barrier(0);                            \
        domfma(Ac, Bc);

    int s = 0;
    for (; s + 2 <= NSTAGE; s += 2) {
        SLOT(s + 0, A0, B0, A1, B1)
        SLOT(s + 1, A1, B1, A0, B0)
    }
    if constexpr (NSTAGE % 2 != 0) {
        domfma(A0, B0);
    }
    #undef SLOT

    #pragma unroll
    for (int rs = 0; rs < WR; ++rs)
        #pragma unroll
        for (int nf = 0; nf < NFW; ++nf)
            #pragma unroll
            for (int r = 0; r < 4; ++r) {
                int v = base + rs * 16 + q * 4 + r;
                if (v < N_VOX)
                    preB[(size_t)v * COUT + ob + nf * 16 + l15] = f2bf(acc[rs][nf][r]);
            }

    float* S = sums + (blockIdx.x & 7) * 256;
    #pragma unroll
    for (int nf = 0; nf < NFW; ++nf) {
        float s1 = 0.f, s2 = 0.f;
        #pragma unroll
        for (int rs = 0; rs < WR; ++rs)
            #pragma unroll
            for (int r = 0; r < 4; ++r) {
                int v = base + rs * 16 + q * 4 + r;
                if (v < N_VOX) {
                    float a = acc[rs][nf][r];
                    s1 += a; s2 += a * a;
                }
            }
        s1 += __shfl_xor(s1, 16); s1 += __shfl_xor(s1, 32);
        s2 += __shfl_xor(s2, 16); s2 += __shfl_xor(s2, 32);
        if (q == 0) {
            atomicAdd(&S[ob + nf * 16 + l15], s1);
            atomicAdd(&S[COUT + ob + nf * 16 + l15], s2);
        }
    }
}

// ============ B-shared MFMA conv (e2/e3/out): distance-2 A prefetch =========
// R10 regime: latency-bound under 27-group barrier lockstep at the LDS-capped
// 2 blocks/CU (4 waves/SIMD). Per slot, ~320cy of cross-wave MFMA barely
// covers L2 A-gather latency -> deepen A to distance 2 (3 rolling buffers,
// slot s consumes A[s%3], prefetches s+2 into A[(s+2)%3]; KK=27 % 3 == 0 so
// a 3-group macro-cycle gives compile-time buffer names). bf reads are per-kk
// (reused reg block) to keep live VGPR ~120 < the (512,4) 128 cap.
// vmcnt at group top (drain stage(g) only, keep slot-loads in flight):
//   g==0: prologue issued stage(0)+[4 nbr + 4 A0 + 4 A1] -> vmcnt(12)
//   g==KK-1: prior group issued 4*SPK A (nbr guarded out) -> vmcnt(4*SPK)
//   else: 4*SPK A + 2 nbr -> vmcnt(4*SPK+2)
template<int CIN, int COUT, int NSPL, bool LAST>
__global__ __launch_bounds__(512, 4) void k_conv_bsh(
    const unsigned short* __restrict__ phi,   // [(N_VOX+1), 4*CIN] bf16
    const int*            __restrict__ nbrP,  // [KK, N_VOX] permuted, pad = N_VOX
    const unsigned short* __restrict__ Wsw,   // [Ktot/8, COUT, 8] bf16
    float*                __restrict__ preF,  // f32 pre (last layer)
    unsigned short*       __restrict__ preB,  // bf16 pre (non-last)
    float*                __restrict__ sums)  // [8][256] per-layer stats copies
{
    constexpr int CIN4   = CIN * 4;            // 128 / 256 / 256
    constexpr int BK     = 64;
    constexpr int SPK    = CIN4 / BK;          // 2 / 4 / 4
    constexpr int NSTAGE = KK * SPK;           // 54 / 108 / 108
    constexpr int KB_G   = 8 * SPK;            // kb rows per k-group: 16 / 32
    constexpr int COUTH  = COUT / NSPL;        // 64
    constexpr int NFW    = COUTH / 16;         // 4
    constexpr int WR     = 2;                  // 32 rows/wave -> M=256/block
    constexpr int NMB    = (N_VOX + 255) / 256; // 196
    constexpr int NBLK   = NMB * NSPL;
    constexpr int PERX   = (NBLK + 7) / 8;
    constexpr int SI     = KB_G / 8;           // stage instr per wave: 2 / 4

    __shared__ short8v ldsB[2][KB_G][64];      // 32KB (e2) / 64KB (e3,out)

    int lb = blockIdx.x;
    int linear = (lb & 7) * PERX + (lb >> 3);  // XCD swizzle
    if (linear >= NBLK) return;
    const int mb = linear / NSPL, h = linear % NSPL;

    const int t = threadIdx.x, lane = t & 63, w = t >> 6;  // w: 0..7
    const int l15 = lane & 15, q = lane >> 4;
    const int base = mb * 256 + w * 32;        // wave's 32 rows
    int vg[WR];
    #pragma unroll
    for (int rs = 0; rs < WR; ++rs) vg[rs] = base + rs * 16 + l15;
    const int ob = h * COUTH;

    int rows[WR], rowsN[WR];
    short8v A0[2][WR], A1[2][WR], A2[2][WR];   // [kk][row-set], 3-deep

    auto stage = [&](int g) {                  // group g's B slice -> LDS
        #pragma unroll
        for (int j = 0; j < SI; ++j) {
            const int m = w * SI + j;          // kb row within group
            gload_lds16(Wsw + ((size_t)(g * KB_G + m) * COUT + ob + lane) * 8,
                        &ldsB[g & 1][m][0]);
        }
    };
    auto loadA = [&](int sp, short8v (&Ab)[2][WR]) {
        if (sp % SPK == 0) {
            #pragma unroll
            for (int rs = 0; rs < WR; ++rs) rows[rs] = rowsN[rs];
        }
        const int c4s = (sp % SPK) * BK;
        #pragma unroll
        for (int rs = 0; rs < WR; ++rs) {
            const unsigned short* p = phi + (size_t)rows[rs] * CIN4 + c4s + q * 8;
            Ab[0][rs] = *(const short8v*)p;
            Ab[1][rs] = *(const short8v*)(p + 32);
        }
        if (sp % SPK == 0) {
            int k2 = sp / SPK + 1;
            if (k2 < KK) {
                #pragma unroll
                for (int rs = 0; rs < WR; ++rs)
                    rowsN[rs] = (vg[rs] < N_VOX) ? nbrP[k2 * N_VOX + vg[rs]] : N_VOX;
            }
        }
    };

    float4v acc[WR][NFW];
    #pragma unroll
    for (int rs = 0; rs < WR; ++rs)
        #pragma unroll
        for (int nf = 0; nf < NFW; ++nf)
            acc[rs][nf] = (float4v){0.f, 0.f, 0.f, 0.f};

    // ---- prologue: stage(0); nbr init; A slots 0 (direct) and 1 (loadA).
    stage(0);
    __builtin_amdgcn_sched_barrier(0);
    #pragma unroll
    for (int rs = 0; rs < WR; ++rs) {
        rows[rs]  = (vg[rs] < N_VOX) ? nbrP[vg[rs]] : N_VOX;
        rowsN[rs] = (vg[rs] < N_VOX) ? nbrP[N_VOX + vg[rs]] : N_VOX;
    }
    #pragma unroll
    for (int rs = 0; rs < WR; ++rs) {
        const unsigned short* p = phi + (size_t)rows[rs] * CIN4 + q * 8;
        A0[0][rs] = *(const short8v*)p;
        A0[1][rs] = *(const short8v*)(p + 32);
    }
    loadA(1, A1);    // 1 % SPK != 0 for SPK in {2,4} -> no row swap

    int sp = 0, g = 0;

    // slot: consume Ac; prefetch slot sp+2 into An; per-kk bf reg reuse
    #define SLOTX(Ac, An)                                                     \
    {                                                                         \
        const int SG = sp % SPK; const int gb = g & 1;                        \
        short8v bfv[NFW];                                                     \
        _Pragma("unroll") for (int nf = 0; nf < NFW; ++nf)                    \
            bfv[nf] = ldsB[gb][SG * 8 + q][nf * 16 + l15];                    \
        if (sp + 2 < NSTAGE) loadA(sp + 2, An);                               \
        __builtin_amdgcn_sched_barrier(0);                                    \
        _Pragma("unroll") for (int nf = 0; nf < NFW; ++nf)                    \
        _Pragma("unroll") for (int rs = 0; rs < WR; ++rs)                     \
            acc[rs][nf] = __builtin_amdgcn_mfma_f32_16x16x32_bf16(            \
                Ac[0][rs], bfv[nf], acc[rs][nf], 0, 0, 0);                    \
        _Pragma("unroll") for (int nf = 0; nf < NFW; ++nf)                    \
            bfv[nf] = ldsB[gb][SG * 8 + 4 + q][nf * 16 + l15];                \
        _Pragma("unroll") for (int nf = 0; nf < NFW; ++nf)                    \
        _Pragma("unroll") for (int rs = 0; rs < WR; ++rs)                     \
            acc[rs][nf] = __builtin_amdgcn_mfma_f32_16x16x32_bf16(            \
                Ac[1][rs], bfv[nf], acc[rs][nf], 0, 0, 0);                    \
        ++sp;                                                                 \
    }

    #define GHDR                                                              \
        if (g == 0) {                                                         \
            asm volatile("s_waitcnt vmcnt(12)" ::: "memory");                 \
        } else if (g == KK - 1) {                                             \
            asm volatile("s_waitcnt vmcnt(%0)" :: "i"(4 * SPK) : "memory");   \
        } else {                                                              \
            asm volatile("s_waitcnt vmcnt(%0)" :: "i"(4 * SPK + 2) : "memory"); \
        }                                                                     \
        __builtin_amdgcn_sched_barrier(0);                                    \
        __builtin_amdgcn_s_barrier();                                         \
        __builtin_amdgcn_sched_barrier(0);                                    \
        if (g + 1 < KK) stage(g + 1);                                         \
        __builtin_amdgcn_sched_barrier(0);

    for (int m = 0; m < KK / 3; ++m) {
        if constexpr (SPK == 2) {
            GHDR SLOTX(A0, A2) SLOTX(A1, A0) ++g;
            GHDR SLOTX(A2, A1) SLOTX(A0, A2) ++g;
            GHDR SLOTX(A1, A0) SLOTX(A2, A1) ++g;
        } else {
            GHDR SLOTX(A0, A2) SLOTX(A1, A0) SLOTX(A2, A1) SLOTX(A0, A2) ++g;
            GHDR SLOTX(A1, A0) SLOTX(A2, A1) SLOTX(A0, A2) SLOTX(A1, A0) ++g;
            GHDR SLOTX(A2, A1) SLOTX(A0, A2) SLOTX(A1, A0) SLOTX(A2, A1) ++g;
        }
    }
    #undef SLOTX
    #undef GHDR

    // ---- store (C/D layout: col=lane&15, row=(lane>>4)*4+r)
    #pragma unroll
    for (int rs = 0; rs < WR; ++rs)
        #pragma unroll
        for (int nf = 0; nf < NFW; ++nf)
            #pragma unroll
            for (int r = 0; r < 4; ++r) {
                int v = base + rs * 16 + q * 4 + r;
                if (v < N_VOX) {
                    if constexpr (LAST)
                        preF[(size_t)v * COUT + ob + nf * 16 + l15] = acc[rs][nf][r];
                    else
                        preB[(size_t)v * COUT + ob + nf * 16 + l15] = f2bf(acc[rs][nf][r]);
                }
            }

    // ---- fused BN stats (exact f32 from accumulators)
    float* S = sums + (blockIdx.x & 7) * 256;
    #pragma unroll
    for (int nf = 0; nf < NFW; ++nf) {
        float s1 = 0.f, s2 = 0.f;
        #pragma unroll
        for (int rs = 0; rs < WR; ++rs)
            #pragma unroll
            for (int r = 0; r < 4; ++r) {
                int v = base + rs * 16 + q * 4 + r;
                if (v < N_VOX) {
                    float a = acc[rs][nf][r];
                    s1 += a; s2 += a * a;
                }
            }
        s1 += __shfl_xor(s1, 16); s1 += __shfl_xor(s1, 32);
        s2 += __shfl_xor(s2, 16); s2 += __shfl_xor(s2, 32);
        if (q == 0) {
            atomicAdd(&S[ob + nf * 16 + l15], s1);
            atomicAdd(&S[COUT + ob + nf * 16 + l15], s2);
        }
    }
}

// ============ BN apply (phi-producing layers; bf16 pre in) ==================
template<int COUT>
__global__ void k_bnapply_phi(const unsigned short* __restrict__ pre,
                              const float* __restrict__ sums,
                              const float* __restrict__ gm, const float* __restrict__ bt,
                              unsigned short* __restrict__ phi) {
    __shared__ float sc[COUT], sh[COUT];
    int t = threadIdx.x;
    if (t < COUT) {
        float s1 = 0.f, s2 = 0.f;
        #pragma unroll
        for (int xo = 0; xo < 8; ++xo) {
            s1 += sums[xo * 256 + t];
            s2 += sums[xo * 256 + COUT + t];
        }
        float mu  = s1 * (1.f / N_VOX);
        float var = s2 * (1.f / N_VOX) - mu*mu;
        float s = rsqrtf(var + 1e-3f) * gm[t];
        sc[t] = s;
        sh[t] = bt[t] - mu * s;
    }
    __syncthreads();
    int tot = (N_VOX + 1) * COUT;
    for (int e = blockIdx.x*256 + t; e < tot; e += gridDim.x*256) {
        int i = e / COUT, c = e % COUT;
        float x = 0.f;
        if (i < N_VOX)
            x = fmaxf(bf2f(pre[(size_t)i*COUT + c]) * sc[c] + sh[c], 0.f);
        float sig = 1.f / (1.f + __expf(-x));
        ushort4 p;
        p.x = f2bf(x * sig);
        p.y = f2bf(__expf(-(x + 1.f) * (x + 1.f)));
        p.z = f2bf(__expf(-x * x));
        p.w = f2bf(__expf(-(x - 1.f) * (x - 1.f)));
        *(ushort4*)&phi[(size_t)e * 4] = p;
    }
}

// ============ last-layer BN finalize: sc/sh table (fused apply in k_dense) ==
__global__ void k_bnfin(const float* __restrict__ sums, const float* __restrict__ gm,
                        const float* __restrict__ bt, float* __restrict__ scsh) {
    int t = threadIdx.x;               // 128 threads
    float s1 = 0.f, s2 = 0.f;
    #pragma unroll
    for (int xo = 0; xo < 8; ++xo) {
        s1 += sums[xo * 256 + t];
        s2 += sums[xo * 256 + 128 + t];
    }
    float mu  = s1 * (1.f / N_VOX);
    float var = s2 * (1.f / N_VOX) - mu*mu;
    float s = rsqrtf(var + 1e-3f) * gm[t];
    scsh[t]       = s;
    scsh[128 + t] = bt[t] - mu * s;
}

// ============ dense fill + fused BN/ReLU: out[b][c*8+z][y][x] ===============
__global__ void k_dense(const float* __restrict__ feat, const int* __restrict__ gridP,
                        const float* __restrict__ scsh, float* __restrict__ out) {
    int e4 = blockIdx.x*256 + threadIdx.x;
    if (e4 >= OUT_ELEMS/4) return;
    int e = e4 * 4;
    int x  = e % WW;                      // multiple of 4
    int y  = (e / WW) % HH;
    int cz = (e / (WW*HH)) % (128*DD);
    int b  = e / (WW*HH*128*DD);
    int c = cz >> 3, z = cz & 7;
    float sc = scsh[c], sh = scsh[128 + c];
    const int* gp = &gridP[((b*PD + z+1)*PH + (y+1))*PW + (x+1)];
    int g0 = gp[0], g1 = gp[1], g2 = gp[2], g3 = gp[3];
    float4 o;
    o.x = (g0 >= 0) ? fmaxf(feat[(size_t)g0*128 + c] * sc + sh, 0.f) : 0.f;
    o.y = (g1 >= 0) ? fmaxf(feat[(size_t)g1*128 + c] * sc + sh, 0.f) : 0.f;
    o.z = (g2 >= 0) ? fmaxf(feat[(size_t)g2*128 + c] * sc + sh, 0.f) : 0.f;
    o.w = (g3 >= 0) ? fmaxf(feat[(size_t)g3*128 + c] * sc + sh, 0.f) : 0.f;
    *(float4*)&out[e] = o;
}

// ============ host side ============
template<int CIN, int COUT, int NSPL>
static void run_block(const float* gm, const float* bt,
                      const int* nbrP, unsigned short* phi, const unsigned short* Wsw,
                      float* sums, unsigned short* preB, hipStream_t stream) {
    constexpr int NMB  = (N_VOX + 63) / 64;
    constexpr int NBLK = NMB * NSPL;
    constexpr int GRID = ((NBLK + 7) / 8) * 8;
    k_conv_mfma<CIN, COUT, NSPL><<<GRID, 64, 0, stream>>>(phi, nbrP, Wsw, preB, sums);
    k_bnapply_phi<COUT><<<512, 256, 0, stream>>>(preB, sums, gm, bt, phi);
}

template<int CIN, int COUT, int NSPL, bool LAST>
static void run_block_bsh(const float* gm, const float* bt,
                          const int* nbrP, unsigned short* phi, const unsigned short* Wsw,
                          float* sums, float* preF, unsigned short* preB,
                          hipStream_t stream) {
    constexpr int NMB  = (N_VOX + 255) / 256;   // 196
    constexpr int NBLK = NMB * NSPL;
    constexpr int GRID = ((NBLK + 7) / 8) * 8;
    k_conv_bsh<CIN, COUT, NSPL, LAST><<<GRID, 512, 0, stream>>>(
        phi, nbrP, Wsw, preF, preB, sums);
    if constexpr (!LAST)
        k_bnapply_phi<COUT><<<512, 256, 0, stream>>>(preB, sums, gm, bt, phi);
    // last layer: BN fused into k_dense via k_bnfin's sc/sh table
}

extern "C" void kernel_launch(void* const* d_in, const int* in_sizes, int n_in,
                              void* d_out, int out_size, void* d_ws, size_t ws_size,
                              hipStream_t stream) {
    const float* vf    = (const float*)d_in[0];
    const int*   coors = (const int*)d_in[1];
    const float* wb[5] = {(const float*)d_in[3],  (const float*)d_in[7],
                          (const float*)d_in[11], (const float*)d_in[15],
                          (const float*)d_in[19]};
    const float* wsp[5]= {(const float*)d_in[4],  (const float*)d_in[8],
                          (const float*)d_in[12], (const float*)d_in[16],
                          (const float*)d_in[20]};
    const float* gm[5] = {(const float*)d_in[5],  (const float*)d_in[9],
                          (const float*)d_in[13], (const float*)d_in[17],
                          (const float*)d_in[21]};
    const float* bt[5] = {(const float*)d_in[6],  (const float*)d_in[10],
                          (const float*)d_in[14], (const float*)d_in[18],
                          (const float*)d_in[22]};

    // workspace bump allocator (256B aligned)
    char* p = (char*)d_ws;
    auto alloc = [&](size_t bytes) {
        char* r = p;
        p += (bytes + 255) & ~(size_t)255;
        return r;
    };
    int*            flags   = (int*)           alloc((size_t)NCELL * 4);
    int*            scanout = (int*)           alloc((size_t)NCELL * 4);
    int*            bsums   = (int*)           alloc(512 * 4);
    int*            vox_at  = (int*)           alloc((size_t)N_VOX * 4);
    int*            gridP   = (int*)           alloc((size_t)GRID_ELEMS * 4);
    int*            nbrP    = (int*)           alloc((size_t)KK * N_VOX * 4);
    unsigned short* Wsw0    = (unsigned short*)alloc((size_t)KK * 64  * 16  * 2);
    unsigned short* Wsw1    = (unsigned short*)alloc((size_t)KK * 64  * 32  * 2);
    unsigned short* Wsw2    = (unsigned short*)alloc((size_t)KK * 128 * 64  * 2);
    unsigned short* Wsw3    = (unsigned short*)alloc((size_t)KK * 256 * 64  * 2);
    unsigned short* Wsw4    = (unsigned short*)alloc((size_t)KK * 256 * 128 * 2);
    unsigned short* phi     = (unsigned short*)alloc((size_t)(N_VOX + 1) * 256 * 2);
    float*          sumsAll = (float*)         alloc(5 * 8 * 256 * 4);
    float*          preF    = (float*)         alloc((size_t)N_VOX * 128 * 4);
    unsigned short* preB    = (unsigned short*)alloc((size_t)N_VOX * 64 * 2);
    float*          scsh    = (float*)         alloc(256 * 4);

    // ---- zero init (workspace re-poisoned to 0xAA before every timed call)
    hipMemsetAsync(flags, 0, (size_t)NCELL * 4, stream);
    hipMemsetAsync(gridP, 0xFF, (size_t)GRID_ELEMS * 4, stream);
    hipMemsetAsync(sumsAll, 0, 5 * 8 * 256 * 4, stream);

    // ---- all weight swizzles in one dispatch
    WswzArgs wa;
    for (int i = 0; i < 5; ++i) { wa.wb[i] = wb[i]; wa.ws[i] = wsp[i]; }
    wa.dst[0] = Wsw0; wa.dst[1] = Wsw1; wa.dst[2] = Wsw2; wa.dst[3] = Wsw3; wa.dst[4] = Wsw4;
    k_wswz_all<<<(1631232 + 255) / 256, 256, 0, stream>>>(wa);

    // ---- spatial permutation + rulebook + phi (k_pos fuses gridP & phi0)
    k_flags<<<(N_VOX+255)/256, 256, 0, stream>>>(coors, flags);
    k_scan1<<<NCELL/1024, 256, 0, stream>>>(flags, scanout, bsums);
    k_scan2<<<1, 512, 0, stream>>>(bsums);
    k_pos  <<<(N_VOX+1+255)/256, 256, 0, stream>>>(vf, coors, scanout, bsums,
                                                   vox_at, gridP, phi);
    k_nbrP <<<(N_VOX+255)/256, 256, 0, stream>>>(coors, vox_at, gridP, nbrP);

    // ---- 5 KAN blocks: in/e1 1-wave; e2/e3/out B-shared M=256, dist-2 A
    run_block<16, 16, 1>(gm[0], bt[0], nbrP, phi, Wsw0, sumsAll + 0*2048, preB, stream);
    run_block<16, 32, 1>(gm[1], bt[1], nbrP, phi, Wsw1, sumsAll + 1*2048, preB, stream);
    run_block_bsh<32, 64,  1, false>(gm[2], bt[2], nbrP, phi, Wsw2, sumsAll + 2*2048, preF, preB, stream);
    run_block_bsh<64, 64,  1, false>(gm[3], bt[3], nbrP, phi, Wsw3, sumsAll + 3*2048, preF, preB, stream);
    run_block_bsh<64, 128, 2, true >(gm[4], bt[4], nbrP, phi, Wsw4, sumsAll + 4*2048, preF, preB, stream);

    // ---- last-layer BN finalize + fused dense output
    k_bnfin<<<1, 128, 0, stream>>>(sumsAll + 4*2048, gm[4], bt[4], scsh);
    k_dense<<<(OUT_ELEMS/4 + 255)/256, 256, 0, stream>>>(preF, gridP, scsh, (float*)d_out);
}

// Round 12
// 614.023 us; speedup vs baseline: 1.0280x; 1.0280x over previous
//
#include <hip/hip_runtime.h>

#define N_VOX 50000
#define BATCH 2
#define DD 8
#define HH 160
#define WW 160
#define PD 10
#define PH 162
#define PW 162
#define KK 27
#define NCELL (BATCH*DD*HH*WW)         // 409600 = 400*1024
#define GRID_ELEMS (BATCH*PD*PH*PW)    // 524880
#define OUT_ELEMS (BATCH*128*DD*HH*WW) // 52,428,800

typedef __attribute__((ext_vector_type(8))) short short8v;
typedef __attribute__((ext_vector_type(4))) float float4v;

__device__ inline unsigned short f2bf(float f) {
    unsigned u = __float_as_uint(f);
    u += 0x7FFFu + ((u >> 16) & 1u);
    return (unsigned short)(u >> 16);
}

__device__ inline void gload_lds16(const void* g, void* l) {
    __builtin_amdgcn_global_load_lds(
        (const __attribute__((address_space(1))) void*)g,
        (__attribute__((address_space(3))) void*)l, 16, 0, 0);
}

// ============ spatial sort: occupancy flags -> prefix sum -> permutation ====
__global__ void k_flags(const int* __restrict__ coors, int* __restrict__ flags) {
    int n = blockIdx.x * 256 + threadIdx.x;
    if (n >= N_VOX) return;
    int b = coors[n*4+0], z = coors[n*4+1], y = coors[n*4+2], x = coors[n*4+3];
    flags[((b*DD + z)*HH + y)*WW + x] = 1;
}

__global__ void k_scan1(const int* __restrict__ flags, int* __restrict__ scanout,
                        int* __restrict__ bsums) {
    __shared__ int s[256];
    int t = threadIdx.x, blk = blockIdx.x;
    int4 v = ((const int4*)(flags + blk*1024))[t];
    int tsum = v.x + v.y + v.z + v.w;
    s[t] = tsum; __syncthreads();
    for (int off = 1; off < 256; off <<= 1) {
        int x = (t >= off) ? s[t-off] : 0;
        __syncthreads(); s[t] += x; __syncthreads();
    }
    int excl = s[t] - tsum;
    int4 o; o.x = excl; o.y = excl + v.x; o.z = o.y + v.y; o.w = o.z + v.z;
    ((int4*)(scanout + blk*1024))[t] = o;
    if (t == 255) bsums[blk] = s[255];
}

__global__ void k_scan2(int* __restrict__ bsums) {
    __shared__ int s[512];
    int t = threadIdx.x;
    int orig = (t < 400) ? bsums[t] : 0;
    s[t] = orig; __syncthreads();
    for (int off = 1; off < 512; off <<= 1) {
        int x = (t >= off) ? s[t-off] : 0;
        __syncthreads(); s[t] += x; __syncthreads();
    }
    if (t < 400) bsums[t] = s[t] - orig;
}

// ============ k_pos: permutation + gridP + phi in ONE pass (R10 fusion) =====
// Thread n knows pos -> writes gridP directly (was k_gridP) and phi[pos]
// (was k_phi0; vf read is now COALESCED vf[n] vs scattered vf[vox_at[i]]).
// FP expressions identical to old k_phi0 -> bitwise-same phi.
__global__ void k_pos(const float* __restrict__ vf, const int* __restrict__ coors,
                      const int* __restrict__ scanout, const int* __restrict__ bsums,
                      int* __restrict__ vox_at, int* __restrict__ gridP,
                      unsigned short* __restrict__ phi) {
    int n = blockIdx.x * 256 + threadIdx.x;
    if (n > N_VOX) return;
    if (n == N_VOX) {                      // pad row = phi(0)
        ushort4 p;
        p.x = f2bf(0.f);
        p.y = f2bf(__expf(-1.f));
        p.z = f2bf(1.f);
        p.w = f2bf(__expf(-1.f));
        #pragma unroll
        for (int c = 0; c < 16; ++c)
            *(ushort4*)&phi[((size_t)N_VOX * 16 + c) * 4] = p;
        return;
    }
    int b = coors[n*4+0], z = coors[n*4+1], y = coors[n*4+2], x = coors[n*4+3];
    int lin = ((b*DD + z)*HH + y)*WW + x;
    int pos = scanout[lin] + bsums[lin >> 10];
    vox_at[pos] = n;
    gridP[((b*PD + z+1)*PH + (y+1))*PW + (x+1)] = pos;
    #pragma unroll
    for (int c = 0; c < 16; ++c) {
        float xv = vf[(size_t)n * 16 + c];
        float sig = 1.f / (1.f + __expf(-xv));
        ushort4 p;
        p.x = f2bf(xv * sig);
        p.y = f2bf(__expf(-(xv + 1.f) * (xv + 1.f)));
        p.z = f2bf(__expf(-xv * xv));
        p.w = f2bf(__expf(-(xv - 1.f) * (xv - 1.f)));
        *(ushort4*)&phi[((size_t)pos * 16 + c) * 4] = p;
    }
}

// iterate permuted index -> coalesced nbrP writes
__global__ void k_nbrP(const int* __restrict__ coors, const int* __restrict__ vox_at,
                       const int* __restrict__ gridP, int* __restrict__ nbrP) {
    int i = blockIdx.x * 256 + threadIdx.x;
    if (i >= N_VOX) return;
    int n = vox_at[i];
    int b = coors[n*4+0], z = coors[n*4+1]+1, y = coors[n*4+2]+1, x = coors[n*4+3]+1;
    int k = 0;
    for (int dz = -1; dz <= 1; ++dz)
        for (int dy = -1; dy <= 1; ++dy)
            for (int dx = -1; dx <= 1; ++dx) {
                int g = gridP[((b*PD + z+dz)*PH + (y+dy))*PW + (x+dx)];
                nbrP[k*N_VOX + i] = (g >= 0) ? g : N_VOX;
                ++k;
            }
}

// ============ all 5 layers' weight swizzle in ONE dispatch ============
struct WswzArgs {
    const float* wb[5];
    const float* ws[5];
    unsigned short* dst[5];
};
__global__ void k_wswz_all(WswzArgs a) {
    constexpr int off[6]   = {0, 27648, 82944, 304128, 746496, 1631232};
    constexpr int lgCI4[5] = {6, 6, 7, 8, 8};
    constexpr int lgCO[5]  = {4, 5, 6, 6, 7};
    int e = blockIdx.x * 256 + threadIdx.x;
    if (e >= off[5]) return;
    int L = 0;
    #pragma unroll
    for (int i = 1; i < 5; ++i) L += (e >= off[i]);
    int el = e - off[L];
    int CIN4 = 1 << lgCI4[L], COUT = 1 << lgCO[L], CIN = CIN4 >> 2;
    int j8   = el & 7;
    int rest = el >> 3;
    int o    = rest & (COUT - 1);
    int kb   = rest >> lgCO[L];
    int kabs = kb * 8 + j8;
    int k  = kabs >> lgCI4[L];
    int c4 = kabs & (CIN4 - 1);
    int c = c4 >> 2, jj = c4 & 3;
    float v = (jj == 0) ? a.wb[L][(k * CIN + c) * COUT + o]
                        : a.ws[L][((k * CIN + c) * 3 + (jj - 1)) * COUT + o];
    a.dst[L][el] = f2bf(v);
}

// ============ 1-wave MFMA conv, M=64 per wave (in/e1 layers) ================
template<int CIN, int COUT, int NSPL>
__global__ __launch_bounds__(64, 2) void k_conv_mfma(
    const unsigned short* __restrict__ phi,
    const int*            __restrict__ nbrP,
    const unsigned short* __restrict__ Wsw,
    float*                __restrict__ pre,
    float*                __restrict__ sums)
{
    constexpr int CIN4   = CIN * 4;
    constexpr int BK     = 64;
    constexpr int SPK    = CIN4 / BK;
    constexpr int NSTAGE = KK * SPK;
    constexpr int COUTH  = COUT / NSPL;
    constexpr int NFW    = COUTH / 16;
    constexpr int WR     = 4;
    constexpr int NMB    = (N_VOX + 63) / 64;
    constexpr int NBLK   = NMB * NSPL;
    constexpr int PERX   = (NBLK + 7) / 8;

    int lb = blockIdx.x;
    int linear = (lb & 7) * PERX + (lb >> 3);
    if (linear >= NBLK) return;
    const int mb = linear / NSPL, h = linear % NSPL;

    const int lane = threadIdx.x & 63;
    const int l15 = lane & 15, q = lane >> 4;
    const int base = mb * 64;
    int vg[WR];
    #pragma unroll
    for (int rs = 0; rs < WR; ++rs) vg[rs] = base + rs * 16 + l15;
    const int ob = h * COUTH;

    const unsigned short* bp = Wsw + (size_t)(q * COUT + ob + l15) * 8;

    int rows[WR], rowsN[WR];
    short8v A0[2][WR], A1[2][WR];
    short8v B0[2][NFW], B1[2][NFW];

    auto loadB = [&](int sp, short8v (&Bb)[2][NFW]) {
        #pragma unroll
        for (int kk = 0; kk < 2; ++kk)
            #pragma unroll
            for (int nf = 0; nf < NFW; ++nf)
                Bb[kk][nf] = *(const short8v*)(bp +
                    ((size_t)(sp * 8 + kk * 4) * COUT + nf * 16) * 8);
    };
    auto loadA = [&](int sp, short8v (&Ab)[2][WR]) {
        if (sp % SPK == 0) {
            #pragma unroll
            for (int rs = 0; rs < WR; ++rs) rows[rs] = rowsN[rs];
        }
        const int c4s = (sp % SPK) * BK;
        #pragma unroll
        for (int rs = 0; rs < WR; ++rs) {
            const unsigned short* p = phi + (size_t)rows[rs] * CIN4 + c4s + q * 8;
            Ab[0][rs] = *(const short8v*)p;
            Ab[1][rs] = *(const short8v*)(p + 32);
        }
        if (sp % SPK == 0) {
            int k2 = sp / SPK + 1;
            if (k2 < KK) {
                #pragma unroll
                for (int rs = 0; rs < WR; ++rs)
                    rowsN[rs] = (vg[rs] < N_VOX) ? nbrP[k2 * N_VOX + vg[rs]] : N_VOX;
            }
        }
    };

    float4v acc[WR][NFW];
    #pragma unroll
    for (int rs = 0; rs < WR; ++rs)
        #pragma unroll
        for (int nf = 0; nf < NFW; ++nf)
            acc[rs][nf] = (float4v){0.f, 0.f, 0.f, 0.f};

    auto domfma = [&](const short8v (&Ab)[2][WR], const short8v (&Bb)[2][NFW]) {
        #pragma unroll
        for (int kk = 0; kk < 2; ++kk)
            #pragma unroll
            for (int nf = 0; nf < NFW; ++nf)
                #pragma unroll
                for (int rs = 0; rs < WR; ++rs)
                    acc[rs][nf] = __builtin_amdgcn_mfma_f32_16x16x32_bf16(
                        Ab[kk][rs], Bb[kk][nf], acc[rs][nf], 0, 0, 0);
    };

    #pragma unroll
    for (int rs = 0; rs < WR; ++rs) {
        rows[rs]  = (vg[rs] < N_VOX) ? nbrP[vg[rs]] : N_VOX;
        rowsN[rs] = (vg[rs] < N_VOX) ? nbrP[N_VOX + vg[rs]] : N_VOX;
    }
    loadB(0, B0);
    #pragma unroll
    for (int rs = 0; rs < WR; ++rs) {
        const unsigned short* p = phi + (size_t)rows[rs] * CIN4 + q * 8;
        A0[0][rs] = *(const short8v*)p;
        A0[1][rs] = *(const short8v*)(p + 32);
    }

    #define SLOT(T, Ac, Bc, An, Bn)                                   \
        if ((T) + 1 < NSTAGE) { loadB((T) + 1, Bn); loadA((T) + 1, An); } \
        __builtin_amdgcn_sched_barrier(0);                            \
        domfma(Ac, Bc);

    int s = 0;
    for (; s + 2 <= NSTAGE; s += 2) {
        SLOT(s + 0, A0, B0, A1, B1)
        SLOT(s + 1, A1, B1, A0, B0)
    }
    if constexpr (NSTAGE % 2 != 0) {
        domfma(A0, B0);
    }
    #undef SLOT

    #pragma unroll
    for (int rs = 0; rs < WR; ++rs)
        #pragma unroll
        for (int nf = 0; nf < NFW; ++nf)
            #pragma unroll
            for (int r = 0; r < 4; ++r) {
                int v = base + rs * 16 + q * 4 + r;
                if (v < N_VOX)
                    pre[(size_t)v * COUT + ob + nf * 16 + l15] = acc[rs][nf][r];
            }

    float* S = sums + (blockIdx.x & 7) * 256;
    #pragma unroll
    for (int nf = 0; nf < NFW; ++nf) {
        float s1 = 0.f, s2 = 0.f;
        #pragma unroll
        for (int rs = 0; rs < WR; ++rs)
            #pragma unroll
            for (int r = 0; r < 4; ++r) {
                int v = base + rs * 16 + q * 4 + r;
                if (v < N_VOX) {
                    float a = acc[rs][nf][r];
                    s1 += a; s2 += a * a;
                }
            }
        s1 += __shfl_xor(s1, 16); s1 += __shfl_xor(s1, 32);
        s2 += __shfl_xor(s2, 16); s2 += __shfl_xor(s2, 32);
        if (q == 0) {
            atomicAdd(&S[ob + nf * 16 + l15], s1);
            atomicAdd(&S[COUT + ob + nf * 16 + l15], s2);
        }
    }
}

// ============ B-shared MFMA conv (e2/e3/out): 8 waves x 32 rows, LDS B ======
// R9 post-mortem: (512,2) = 2 waves/EU min -> 1 block/CU = 8 waves/CU, same
// residency as R8 -> B-staging cut gave ~0. The kernel is latency-bound under
// the 27-group barrier lockstep: per group a SIMD had 2 waves x ~320cy MFMA
// vs ~600cy A-gather latency. Fix: __launch_bounds__(512,4) -> VGPR cap 128,
// 2 blocks/CU = 16 waves/CU (LDS 2x64KB=128<=160KB) -> 2x latency cover.
// Live regs ~116 (acc32+Adbuf32+bf32+addr) so 128 should hold w/o hot spills.
// (R11 tried distance-2 A prefetch + bf16 pre on top: -16us regression and
// absmax 0.14->0.20; reverted per pre-committed falsifier. This R10 form is
// the measured optimum of the bsh structure: 615.3us, absmax 0.140625.)
template<int CIN, int COUT, int NSPL>
__global__ __launch_bounds__(512, 4) void k_conv_bsh(
    const unsigned short* __restrict__ phi,   // [(N_VOX+1), 4*CIN] bf16
    const int*            __restrict__ nbrP,  // [KK, N_VOX] permuted, pad = N_VOX
    const unsigned short* __restrict__ Wsw,   // [Ktot/8, COUT, 8] bf16
    float*                __restrict__ pre,   // [N_VOX, COUT]
    float*                __restrict__ sums)  // [8][256] per-layer stats copies
{
    constexpr int CIN4   = CIN * 4;            // 128 / 256 / 256
    constexpr int BK     = 64;
    constexpr int SPK    = CIN4 / BK;          // 2 / 4 / 4
    constexpr int NSTAGE = KK * SPK;           // 54 / 108 / 108
    constexpr int KB_G   = 8 * SPK;            // kb rows per k-group: 16 / 32
    constexpr int COUTH  = COUT / NSPL;        // 64
    constexpr int NFW    = COUTH / 16;         // 4
    constexpr int WR     = 2;                  // 32 rows/wave -> M=256/block
    constexpr int NMB    = (N_VOX + 255) / 256; // 196
    constexpr int NBLK   = NMB * NSPL;
    constexpr int PERX   = (NBLK + 7) / 8;
    constexpr int SI     = KB_G / 8;           // stage instr per wave: 2 / 4

    __shared__ short8v ldsB[2][KB_G][64];      // 32KB (e2) / 64KB (e3,out)

    int lb = blockIdx.x;
    int linear = (lb & 7) * PERX + (lb >> 3);  // XCD swizzle
    if (linear >= NBLK) return;
    const int mb = linear / NSPL, h = linear % NSPL;

    const int t = threadIdx.x, lane = t & 63, w = t >> 6;  // w: 0..7
    const int l15 = lane & 15, q = lane >> 4;
    const int base = mb * 256 + w * 32;        // wave's 32 rows
    int vg[WR];
    #pragma unroll
    for (int rs = 0; rs < WR; ++rs) vg[rs] = base + rs * 16 + l15;
    const int ob = h * COUTH;

    int rows[WR], rowsN[WR];
    short8v A0[2][WR], A1[2][WR];              // [kk][row-set], reg dbuf

    auto stage = [&](int g) {                  // group g's B slice -> LDS
        #pragma unroll
        for (int j = 0; j < SI; ++j) {
            const int m = w * SI + j;          // kb row within group
            gload_lds16(Wsw + ((size_t)(g * KB_G + m) * COUT + ob + lane) * 8,
                        &ldsB[g & 1][m][0]);
        }
    };
    auto loadA = [&](int sp, short8v (&Ab)[2][WR]) {
        if (sp % SPK == 0) {
            #pragma unroll
            for (int rs = 0; rs < WR; ++rs) rows[rs] = rowsN[rs];
        }
        const int c4s = (sp % SPK) * BK;
        #pragma unroll
        for (int rs = 0; rs < WR; ++rs) {
            const unsigned short* p = phi + (size_t)rows[rs] * CIN4 + c4s + q * 8;
            Ab[0][rs] = *(const short8v*)p;
            Ab[1][rs] = *(const short8v*)(p + 32);
        }
        if (sp % SPK == 0) {
            int k2 = sp / SPK + 1;
            if (k2 < KK) {
                #pragma unroll
                for (int rs = 0; rs < WR; ++rs)
                    rowsN[rs] = (vg[rs] < N_VOX) ? nbrP[k2 * N_VOX + vg[rs]] : N_VOX;
            }
        }
    };

    float4v acc[WR][NFW];
    #pragma unroll
    for (int rs = 0; rs < WR; ++rs)
        #pragma unroll
        for (int nf = 0; nf < NFW; ++nf)
            acc[rs][nf] = (float4v){0.f, 0.f, 0.f, 0.f};

    // ---- prologue: stage(0) FIRST, then nbr init + direct A(0).
    stage(0);
    __builtin_amdgcn_sched_barrier(0);
    #pragma unroll
    for (int rs = 0; rs < WR; ++rs) {
        rows[rs]  = (vg[rs] < N_VOX) ? nbrP[vg[rs]] : N_VOX;
        rowsN[rs] = (vg[rs] < N_VOX) ? nbrP[N_VOX + vg[rs]] : N_VOX;
    }
    #pragma unroll
    for (int rs = 0; rs < WR; ++rs) {
        const unsigned short* p = phi + (size_t)rows[rs] * CIN4 + q * 8;
        A0[0][rs] = *(const short8v*)p;
        A0[1][rs] = *(const short8v*)(p + 32);
    }
    // outstanding: stage(0)[SI] then 4 nbr + 4 A0 -> drain stage: vmcnt(8)

    int sp = 0;
    #define SLOTB(SG, Ac, An)                                                 \
    {                                                                         \
        short8v bf[2][NFW];                                                   \
        _Pragma("unroll") for (int kk = 0; kk < 2; ++kk)                      \
        _Pragma("unroll") for (int nf = 0; nf < NFW; ++nf)                    \
            bf[kk][nf] = ldsB[g & 1][(SG) * 8 + kk * 4 + q][nf * 16 + l15];   \
        if (sp + 1 < NSTAGE) loadA(sp + 1, An);                               \
        __builtin_amdgcn_sched_barrier(0);                                    \
        _Pragma("unroll") for (int kk = 0; kk < 2; ++kk)                      \
        _Pragma("unroll") for (int nf = 0; nf < NFW; ++nf)                    \
        _Pragma("unroll") for (int rs = 0; rs < WR; ++rs)                     \
            acc[rs][nf] = __builtin_amdgcn_mfma_f32_16x16x32_bf16(            \
                Ac[kk][rs], bf[kk][nf], acc[rs][nf], 0, 0, 0);                \
        ++sp;                                                                 \
    }

    for (int g = 0; g < KK; ++g) {
        // drain this group's stage while keeping prior group's A-loads in
        // flight. Prior group issued 4*SPK A-loads, +2 nbr only if g<=KK-2
        // (its k2 = g+1 < KK). g==0: prologue issued 8 non-stage loads.
        if (g == 0) {
            asm volatile("s_waitcnt vmcnt(8)" ::: "memory");
        } else if (g == KK - 1) {
            asm volatile("s_waitcnt vmcnt(%0)" :: "i"(4 * SPK) : "memory");
        } else {
            asm volatile("s_waitcnt vmcnt(%0)" :: "i"(4 * SPK + 2) : "memory");
        }
        __builtin_amdgcn_sched_barrier(0);
        __builtin_amdgcn_s_barrier();
        __builtin_amdgcn_sched_barrier(0);
        if (g + 1 < KK) stage(g + 1);
        __builtin_amdgcn_sched_barrier(0);
        SLOTB(0, A0, A1)
        SLOTB(1, A1, A0)
        if constexpr (SPK == 4) {
            SLOTB(2, A0, A1)
            SLOTB(3, A1, A0)
        }
    }
    #undef SLOTB

    // ---- store (C/D layout: col=lane&15, row=(lane>>4)*4+r)
    #pragma unroll
    for (int rs = 0; rs < WR; ++rs)
        #pragma unroll
        for (int nf = 0; nf < NFW; ++nf)
            #pragma unroll
            for (int r = 0; r < 4; ++r) {
                int v = base + rs * 16 + q * 4 + r;
                if (v < N_VOX)
                    pre[(size_t)v * COUT + ob + nf * 16 + l15] = acc[rs][nf][r];
            }

    // ---- fused BN stats
    float* S = sums + (blockIdx.x & 7) * 256;
    #pragma unroll
    for (int nf = 0; nf < NFW; ++nf) {
        float s1 = 0.f, s2 = 0.f;
        #pragma unroll
        for (int rs = 0; rs < WR; ++rs)
            #pragma unroll
            for (int r = 0; r < 4; ++r) {
                int v = base + rs * 16 + q * 4 + r;
                if (v < N_VOX) {
                    float a = acc[rs][nf][r];
                    s1 += a; s2 += a * a;
                }
            }
        s1 += __shfl_xor(s1, 16); s1 += __shfl_xor(s1, 32);
        s2 += __shfl_xor(s2, 16); s2 += __shfl_xor(s2, 32);
        if (q == 0) {
            atomicAdd(&S[ob + nf * 16 + l15], s1);
            atomicAdd(&S[COUT + ob + nf * 16 + l15], s2);
        }
    }
}

// ============ BN apply (phi-producing layers only) ==========================
template<int COUT>
__global__ void k_bnapply_phi(const float* __restrict__ pre, const float* __restrict__ sums,
                              const float* __restrict__ gm, const float* __restrict__ bt,
                              unsigned short* __restrict__ phi) {
    __shared__ float sc[COUT], sh[COUT];
    int t = threadIdx.x;
    if (t < COUT) {
        float s1 = 0.f, s2 = 0.f;
        #pragma unroll
        for (int xo = 0; xo < 8; ++xo) {
            s1 += sums[xo * 256 + t];
            s2 += sums[xo * 256 + COUT + t];
        }
        float mu  = s1 * (1.f / N_VOX);
        float var = s2 * (1.f / N_VOX) - mu*mu;
        float s = rsqrtf(var + 1e-3f) * gm[t];
        sc[t] = s;
        sh[t] = bt[t] - mu * s;
    }
    __syncthreads();
    int tot = (N_VOX + 1) * COUT;
    for (int e = blockIdx.x*256 + t; e < tot; e += gridDim.x*256) {
        int i = e / COUT, c = e % COUT;
        float x = 0.f;
        if (i < N_VOX) x = fmaxf(pre[(size_t)i*COUT + c] * sc[c] + sh[c], 0.f);
        float sig = 1.f / (1.f + __expf(-x));
        ushort4 p;
        p.x = f2bf(x * sig);
        p.y = f2bf(__expf(-(x + 1.f) * (x + 1.f)));
        p.z = f2bf(__expf(-x * x));
        p.w = f2bf(__expf(-(x - 1.f) * (x - 1.f)));
        *(ushort4*)&phi[(size_t)e * 4] = p;
    }
}

// ============ last-layer BN finalize: sc/sh table (fused apply in k_dense) ==
__global__ void k_bnfin(const float* __restrict__ sums, const float* __restrict__ gm,
                        const float* __restrict__ bt, float* __restrict__ scsh) {
    int t = threadIdx.x;               // 128 threads
    float s1 = 0.f, s2 = 0.f;
    #pragma unroll
    for (int xo = 0; xo < 8; ++xo) {
        s1 += sums[xo * 256 + t];
        s2 += sums[xo * 256 + 128 + t];
    }
    float mu  = s1 * (1.f / N_VOX);
    float var = s2 * (1.f / N_VOX) - mu*mu;
    float s = rsqrtf(var + 1e-3f) * gm[t];
    scsh[t]       = s;
    scsh[128 + t] = bt[t] - mu * s;
}

// ============ dense fill + fused BN/ReLU: out[b][c*8+z][y][x] ===============
__global__ void k_dense(const float* __restrict__ feat, const int* __restrict__ gridP,
                        const float* __restrict__ scsh, float* __restrict__ out) {
    int e4 = blockIdx.x*256 + threadIdx.x;
    if (e4 >= OUT_ELEMS/4) return;
    int e = e4 * 4;
    int x  = e % WW;                      // multiple of 4
    int y  = (e / WW) % HH;
    int cz = (e / (WW*HH)) % (128*DD);
    int b  = e / (WW*HH*128*DD);
    int c = cz >> 3, z = cz & 7;
    float sc = scsh[c], sh = scsh[128 + c];
    const int* gp = &gridP[((b*PD + z+1)*PH + (y+1))*PW + (x+1)];
    int g0 = gp[0], g1 = gp[1], g2 = gp[2], g3 = gp[3];
    float4 o;
    o.x = (g0 >= 0) ? fmaxf(feat[(size_t)g0*128 + c] * sc + sh, 0.f) : 0.f;
    o.y = (g1 >= 0) ? fmaxf(feat[(size_t)g1*128 + c] * sc + sh, 0.f) : 0.f;
    o.z = (g2 >= 0) ? fmaxf(feat[(size_t)g2*128 + c] * sc + sh, 0.f) : 0.f;
    o.w = (g3 >= 0) ? fmaxf(feat[(size_t)g3*128 + c] * sc + sh, 0.f) : 0.f;
    *(float4*)&out[e] = o;
}

// ============ host side ============
template<int CIN, int COUT, int NSPL>
static void run_block(const float* gm, const float* bt,
                      const int* nbrP, unsigned short* phi, const unsigned short* Wsw,
                      float* sums, float* pre, hipStream_t stream) {
    constexpr int NMB  = (N_VOX + 63) / 64;
    constexpr int NBLK = NMB * NSPL;
    constexpr int GRID = ((NBLK + 7) / 8) * 8;
    k_conv_mfma<CIN, COUT, NSPL><<<GRID, 64, 0, stream>>>(phi, nbrP, Wsw, pre, sums);
    k_bnapply_phi<COUT><<<512, 256, 0, stream>>>(pre, sums, gm, bt, phi);
}

template<int CIN, int COUT, int NSPL>
static void run_block_bsh(const float* gm, const float* bt,
                          const int* nbrP, unsigned short* phi, const unsigned short* Wsw,
                          float* sums, float* pre, bool last, hipStream_t stream) {
    constexpr int NMB  = (N_VOX + 255) / 256;   // 196
    constexpr int NBLK = NMB * NSPL;
    constexpr int GRID = ((NBLK + 7) / 8) * 8;
    k_conv_bsh<CIN, COUT, NSPL><<<GRID, 512, 0, stream>>>(phi, nbrP, Wsw, pre, sums);
    if (!last)
        k_bnapply_phi<COUT><<<512, 256, 0, stream>>>(pre, sums, gm, bt, phi);
    // last layer: BN fused into k_dense via k_bnfin's sc/sh table
}

extern "C" void kernel_launch(void* const* d_in, const int* in_sizes, int n_in,
                              void* d_out, int out_size, void* d_ws, size_t ws_size,
                              hipStream_t stream) {
    const float* vf    = (const float*)d_in[0];
    const int*   coors = (const int*)d_in[1];
    const float* wb[5] = {(const float*)d_in[3],  (const float*)d_in[7],
                          (const float*)d_in[11], (const float*)d_in[15],
                          (const float*)d_in[19]};
    const float* wsp[5]= {(const float*)d_in[4],  (const float*)d_in[8],
                          (const float*)d_in[12], (const float*)d_in[16],
                          (const float*)d_in[20]};
    const float* gm[5] = {(const float*)d_in[5],  (const float*)d_in[9],
                          (const float*)d_in[13], (const float*)d_in[17],
                          (const float*)d_in[21]};
    const float* bt[5] = {(const float*)d_in[6],  (const float*)d_in[10],
                          (const float*)d_in[14], (const float*)d_in[18],
                          (const float*)d_in[22]};

    // workspace bump allocator (256B aligned)
    char* p = (char*)d_ws;
    auto alloc = [&](size_t bytes) {
        char* r = p;
        p += (bytes + 255) & ~(size_t)255;
        return r;
    };
    int*            flags   = (int*)           alloc((size_t)NCELL * 4);
    int*            scanout = (int*)           alloc((size_t)NCELL * 4);
    int*            bsums   = (int*)           alloc(512 * 4);
    int*            vox_at  = (int*)           alloc((size_t)N_VOX * 4);
    int*            gridP   = (int*)           alloc((size_t)GRID_ELEMS * 4);
    int*            nbrP    = (int*)           alloc((size_t)KK * N_VOX * 4);
    unsigned short* Wsw0    = (unsigned short*)alloc((size_t)KK * 64  * 16  * 2);
    unsigned short* Wsw1    = (unsigned short*)alloc((size_t)KK * 64  * 32  * 2);
    unsigned short* Wsw2    = (unsigned short*)alloc((size_t)KK * 128 * 64  * 2);
    unsigned short* Wsw3    = (unsigned short*)alloc((size_t)KK * 256 * 64  * 2);
    unsigned short* Wsw4    = (unsigned short*)alloc((size_t)KK * 256 * 128 * 2);
    unsigned short* phi     = (unsigned short*)alloc((size_t)(N_VOX + 1) * 256 * 2);
    float*          sumsAll = (float*)         alloc(5 * 8 * 256 * 4);
    float*          pre     = (float*)         alloc((size_t)N_VOX * 128 * 4);
    float*          scsh    = (float*)         alloc(256 * 4);

    // ---- zero init (workspace re-poisoned to 0xAA before every timed call)
    hipMemsetAsync(flags, 0, (size_t)NCELL * 4, stream);
    hipMemsetAsync(gridP, 0xFF, (size_t)GRID_ELEMS * 4, stream);
    hipMemsetAsync(sumsAll, 0, 5 * 8 * 256 * 4, stream);

    // ---- all weight swizzles in one dispatch
    WswzArgs wa;
    for (int i = 0; i < 5; ++i) { wa.wb[i] = wb[i]; wa.ws[i] = wsp[i]; }
    wa.dst[0] = Wsw0; wa.dst[1] = Wsw1; wa.dst[2] = Wsw2; wa.dst[3] = Wsw3; wa.dst[4] = Wsw4;
    k_wswz_all<<<(1631232 + 255) / 256, 256, 0, stream>>>(wa);

    // ---- spatial permutation + rulebook + phi (k_pos fuses gridP & phi0)
    k_flags<<<(N_VOX+255)/256, 256, 0, stream>>>(coors, flags);
    k_scan1<<<NCELL/1024, 256, 0, stream>>>(flags, scanout, bsums);
    k_scan2<<<1, 512, 0, stream>>>(bsums);
    k_pos  <<<(N_VOX+1+255)/256, 256, 0, stream>>>(vf, coors, scanout, bsums,
                                                   vox_at, gridP, phi);
    k_nbrP <<<(N_VOX+255)/256, 256, 0, stream>>>(coors, vox_at, gridP, nbrP);

    // ---- 5 KAN blocks: in/e1 R4 1-wave kernels; e2/e3/out B-shared M=256
    run_block<16, 16, 1>(gm[0], bt[0], nbrP, phi, Wsw0, sumsAll + 0*2048, pre, stream);
    run_block<16, 32, 1>(gm[1], bt[1], nbrP, phi, Wsw1, sumsAll + 1*2048, pre, stream);
    run_block_bsh<32, 64,  1>(gm[2], bt[2], nbrP, phi, Wsw2, sumsAll + 2*2048, pre, false, stream);
    run_block_bsh<64, 64,  1>(gm[3], bt[3], nbrP, phi, Wsw3, sumsAll + 3*2048, pre, false, stream);
    run_block_bsh<64, 128, 2>(gm[4], bt[4], nbrP, phi, Wsw4, sumsAll + 4*2048, pre, true,  stream);

    // ---- last-layer BN finalize + fused dense output
    k_bnfin<<<1, 128, 0, stream>>>(sumsAll + 4*2048, gm[4], bt[4], scsh);
    k_dense<<<(OUT_ELEMS/4 + 255)/256, 256, 0, stream>>>(pre, gridP, scsh, (float*)d_out);
}